// Round 11
// baseline (728.410 us; speedup 1.0000x reference)
//
#include <hip/hip_runtime.h>
#include <hip/hip_bf16.h>

typedef unsigned int u32;
typedef unsigned short u16;
typedef __bf16 bf16x8 __attribute__((ext_vector_type(8)));
typedef float f32x4 __attribute__((ext_vector_type(4)));

__device__ __forceinline__ u16 f2b(float f) {
    __bf16 b = (__bf16)f;
    return __builtin_bit_cast(u16, b);
}
__device__ __forceinline__ float b2f(u16 v) {
    u32 x = ((u32)v) << 16;
    return __builtin_bit_cast(float, x);
}

__device__ __forceinline__ void gld_lds16(const void* g, void* l) {
    __builtin_amdgcn_global_load_lds(
        (const __attribute__((address_space(1))) u32*)(size_t)g,
        (__attribute__((address_space(3))) u32*)(u32)(size_t)l,
        16, 0, 0);
}

#define BARRIER __builtin_amdgcn_s_barrier()
#define LGKM0 asm volatile("s_waitcnt lgkmcnt(0)" ::: "memory")
#define VMC4 asm volatile("s_waitcnt vmcnt(4)" ::: "memory")
#define VMC6 asm volatile("s_waitcnt vmcnt(6)" ::: "memory")
#define VMC0 asm volatile("s_waitcnt vmcnt(0)" ::: "memory")
#define MFMA16(d, a, b) d = __builtin_amdgcn_mfma_f32_16x16x32_bf16(a, b, d, 0, 0, 0)

// ================= 256x256 8-phase bf16 GEMM (16x16x32 MFMA) =================
// Round-9 validated schedule: 8 waves (2Mx4N), BK=64, 128 KiB LDS,
// XOR swizzle byte^=((row&7)<<4), read balance 8/4/8/4 with bL pipelined
// one K-tile ahead (VMC4 at P3-end), P4 MFMA reg-only (no entry barrier).

template<int GRAN>
__device__ __forceinline__ void stage_half(
    const u16* __restrict__ src, int ld, int rowbase, int kk,
    u16* ldsregion, int h, int w, int l)
{
    #pragma unroll
    for (int j = 0; j < 2; ++j) {
        const int c = w * 2 + j;
        const int o = c * 1024 + l * 16;               // linear dest byte in 16KB half
        const int os = o ^ (((o >> 7) & 7) << 4);      // inverse-swizzled source offset
        const int pos = o >> 7;                        // lds row
        const int row = ((pos / GRAN) * 2 + h) * GRAN + (pos & (GRAN - 1));
        const u16* g = src + (long)(rowbase + row) * ld + kk + ((os & 127) >> 1);
        gld_lds16(g, ldsregion + c * 512);
    }
}

__device__ __forceinline__ bf16x8 ldfrag(const u16* region, int pos, int col) {
    const int o = (pos * 128 + col * 2) ^ ((pos & 7) << 4);
    return *reinterpret_cast<const bf16x8*>(reinterpret_cast<const char*>(region) + o);
}

template<int CB>
__device__ __forceinline__ void ktile_group(
    const u16* __restrict__ A, int lda, const u16* __restrict__ BT, int ldb,
    int brow, int bcol, int kkA1, int kkR,
    int wr, int wc, int r4, int q8, int w, int l,
    u16 (&lds)[2][4][8192], f32x4 (&acc)[8][4],
    bf16x8 (&bLu)[2][2], bf16x8 (&bLf)[2][2])
{
    bf16x8 aL[4][2], aH[4][2], bH[2][2];

    // ---- P1: quadrant (m0-3, n0-1); reads aL (8)
    #pragma unroll
    for (int m = 0; m < 4; ++m) {
        aL[m][0] = ldfrag(lds[CB][0], wr * 64 + m * 16 + r4, q8);
        aL[m][1] = ldfrag(lds[CB][0], wr * 64 + m * 16 + r4, 32 + q8);
    }
    stage_half<64>(A, lda, brow, kkA1, &lds[1 - CB][1][0], 1, w, l);
    BARRIER; LGKM0;
    __builtin_amdgcn_s_setprio(1);
    #pragma unroll
    for (int m = 0; m < 4; ++m)
        #pragma unroll
        for (int n = 0; n < 2; ++n) {
            MFMA16(acc[m][n], aL[m][0], bLu[n][0]);
            MFMA16(acc[m][n], aL[m][1], bLu[n][1]);
        }
    __builtin_amdgcn_s_setprio(0);
    BARRIER;

    // ---- P2: quadrant (m0-3, n2-3); reads bH (4)
    #pragma unroll
    for (int n = 0; n < 2; ++n) {
        bH[n][0] = ldfrag(lds[CB][3], wc * 32 + n * 16 + r4, q8);
        bH[n][1] = ldfrag(lds[CB][3], wc * 32 + n * 16 + r4, 32 + q8);
    }
    stage_half<64>(A, lda, brow, kkR, &lds[CB][0][0], 0, w, l);
    BARRIER; LGKM0;
    __builtin_amdgcn_s_setprio(1);
    #pragma unroll
    for (int m = 0; m < 4; ++m)
        #pragma unroll
        for (int n = 0; n < 2; ++n) {
            MFMA16(acc[m][2 + n], aL[m][0], bH[n][0]);
            MFMA16(acc[m][2 + n], aL[m][1], bH[n][1]);
        }
    __builtin_amdgcn_s_setprio(0);
    BARRIER;

    // ---- P3: quadrant (m4-7, n2-3); reads aH (8); VMC4 certifies other buffer
    #pragma unroll
    for (int m = 0; m < 4; ++m) {
        aH[m][0] = ldfrag(lds[CB][1], wr * 64 + m * 16 + r4, q8);
        aH[m][1] = ldfrag(lds[CB][1], wr * 64 + m * 16 + r4, 32 + q8);
    }
    stage_half<32>(BT, ldb, bcol, kkR, &lds[CB][2][0], 0, w, l);
    BARRIER; LGKM0;
    __builtin_amdgcn_s_setprio(1);
    #pragma unroll
    for (int m = 0; m < 4; ++m)
        #pragma unroll
        for (int n = 0; n < 2; ++n) {
            MFMA16(acc[4 + m][2 + n], aH[m][0], bH[n][0]);
            MFMA16(acc[4 + m][2 + n], aH[m][1], bH[n][1]);
        }
    __builtin_amdgcn_s_setprio(0);
    VMC4;
    BARRIER;

    // ---- P4: quadrant (m4-7, n0-1); register-only MFMA -> no entry barrier.
    stage_half<32>(BT, ldb, bcol, kkR, &lds[CB][3][0], 1, w, l);
    #pragma unroll
    for (int n = 0; n < 2; ++n) {
        bLf[n][0] = ldfrag(lds[1 - CB][2], wc * 32 + n * 16 + r4, q8);
        bLf[n][1] = ldfrag(lds[1 - CB][2], wc * 32 + n * 16 + r4, 32 + q8);
    }
    __builtin_amdgcn_s_setprio(1);
    #pragma unroll
    for (int m = 0; m < 4; ++m)
        #pragma unroll
        for (int n = 0; n < 2; ++n) {
            MFMA16(acc[4 + m][n], aH[m][0], bLu[n][0]);
            MFMA16(acc[4 + m][n], aH[m][1], bLu[n][1]);
        }
    __builtin_amdgcn_s_setprio(0);
    BARRIER;
}

__device__ __forceinline__ void gemm_body(
    int bid, int t,
    const u16* __restrict__ A, int lda,
    const u16* __restrict__ BT, int ldb,
    u16* __restrict__ C, int ldc, int K,
    u16 (&lds)[2][4][8192])
{
    const int w = t >> 6, l = t & 63;
    const int wr = w >> 2, wc = w & 3;
    const int r4 = l & 15, q8 = (l >> 4) * 8;
    // XCD-aware bijective swizzle for 512 workgroups (8x8 block chunk/XCD).
    const int xcd = bid & 7, within = bid >> 3;
    const int by = (xcd >> 2) * 8 + (within >> 3);
    const int bx = (xcd & 3) * 8 + (within & 7);
    const int brow = by * 256, bcol = bx * 256;
    const int NT = K >> 6;

    f32x4 acc[8][4];
    #pragma unroll
    for (int m = 0; m < 8; ++m)
        #pragma unroll
        for (int n = 0; n < 4; ++n)
            acc[m][n] = (f32x4){0.f, 0.f, 0.f, 0.f};

    stage_half<64>(A, lda, brow, 0, &lds[0][0][0], 0, w, l);
    stage_half<32>(BT, ldb, bcol, 0, &lds[0][2][0], 0, w, l);
    stage_half<32>(BT, ldb, bcol, 0, &lds[0][3][0], 1, w, l);
    stage_half<64>(A, lda, brow, 0, &lds[0][1][0], 1, w, l);
    stage_half<64>(A, lda, brow, 64, &lds[1][0][0], 0, w, l);
    stage_half<32>(BT, ldb, bcol, 64, &lds[1][2][0], 0, w, l);
    stage_half<32>(BT, ldb, bcol, 64, &lds[1][3][0], 1, w, l);
    VMC6;
    BARRIER;

    bf16x8 bl0[2][2], bl1[2][2];
    #pragma unroll
    for (int n = 0; n < 2; ++n) {
        bl0[n][0] = ldfrag(lds[0][2], wc * 32 + n * 16 + r4, q8);
        bl0[n][1] = ldfrag(lds[0][2], wc * 32 + n * 16 + r4, 32 + q8);
    }

    for (int i = 0; i < (NT >> 1); ++i) {
        const int U = 2 * i;
        int tV = U + 1;
        int tU2 = U + 2;
        int tV2 = U + 3;
        if (tU2 >= NT) tU2 -= NT;
        if (tV2 >= NT) tV2 -= NT;
        const int kkV = (tV >= NT ? tV - NT : tV) << 6;
        const int kkU2 = tU2 << 6;
        const int kkV2 = tV2 << 6;

        ktile_group<0>(A, lda, BT, ldb, brow, bcol, kkV, kkU2,
                       wr, wc, r4, q8, w, l, lds, acc, bl0, bl1);
        ktile_group<1>(A, lda, BT, ldb, brow, bcol, kkU2, kkV2,
                       wr, wc, r4, q8, w, l, lds, acc, bl1, bl0);
    }

    VMC0;

    const int crow0 = (l >> 4) * 4;
    const int ccol = l & 15;
    #pragma unroll
    for (int m = 0; m < 8; ++m) {
        #pragma unroll
        for (int n = 0; n < 4; ++n) {
            int gr = brow + wr * 128 + m * 16 + crow0;
            int gc = bcol + wc * 64 + n * 16 + ccol;
            #pragma unroll
            for (int r = 0; r < 4; ++r)
                C[(long)(gr + r) * ldc + gc] = f2b(acc[m][n][r]);
        }
    }
}

// ---------------- fc2 GEMM (standalone) ----------------
__global__ __launch_bounds__(512, 2) void gemm256(
    const u16* __restrict__ A, int lda,
    const u16* __restrict__ BT, int ldb,
    u16* __restrict__ C, int ldc, int K)
{
    __shared__ __align__(16) u16 lds[2][4][8192];   // 128 KiB
    gemm_body(blockIdx.y * 32 + blockIdx.x, threadIdx.x,
              A, lda, BT, ldb, C, ldc, K, lds);
}

// ------- fused: fc1 GEMM (blocks 0..511) + w2 transpose (blocks 512+) -------
// fc1 needs only XB/W1T (produced earlier); transpose produces W2T consumed
// only by fc2 (later) -> no intra-grid dependency. BW-bound transpose blocks
// overlap the compute-bound fc1 blocks.
__global__ __launch_bounds__(512, 2) void fc1_w2t_kernel(
    const u16* __restrict__ XB, const u16* __restrict__ W1T,
    u16* __restrict__ Yb,
    const float* __restrict__ w2, u16* __restrict__ W2T)
{
    __shared__ __align__(16) u16 lds[2][4][8192];   // 128 KiB
    const int t = threadIdx.x;
    if (blockIdx.x < 512) {
        gemm_body(blockIdx.x, t, XB, 256, W1T, 256, Yb, 8192, 256, lds);
        return;
    }
    // w2 transpose: 128(rows) x 64(cols) f32 tile -> W2T bf16
    float (*tile)[65] = reinterpret_cast<float(*)[65]>(&lds[0][0][0]); // 33.3 KB
    const int tid = blockIdx.x - 512;            // 0..8191
    const int ct = tid & 127, rt = tid >> 7;     // 128 col-tiles, 64 row-tiles
    const int r0 = rt * 128, c0 = ct * 64;
    #pragma unroll
    for (int i = 0; i < 4; ++i) {
        int idx = t + i * 512;                   // 2048 float4 slots
        int r = idx >> 4;                        // 128 rows, 16 float4/row
        int c = (idx & 15) * 4;
        float4 f = *reinterpret_cast<const float4*>(&w2[(long)(r0 + r) * 8192 + c0 + c]);
        tile[r][c] = f.x; tile[r][c + 1] = f.y; tile[r][c + 2] = f.z; tile[r][c + 3] = f.w;
    }
    __syncthreads();
    const int rr = t >> 3;                       // out row within tile (= input col), 0..63
    const int ch = t & 7;                        // 16-wide chunk of out cols
    u32 pk[8];
    #pragma unroll
    for (int j = 0; j < 8; ++j) {
        int cc = ch * 16 + j * 2;
        pk[j] = (u32)f2b(tile[cc][rr]) | ((u32)f2b(tile[cc + 1][rr]) << 16);
    }
    u16* dst = &W2T[(long)(c0 + rr) * 8192 + r0 + ch * 16];
    uint4 o0; o0.x = pk[0]; o0.y = pk[1]; o0.z = pk[2]; o0.w = pk[3];
    uint4 o1; o1.x = pk[4]; o1.y = pk[5]; o1.z = pk[6]; o1.w = pk[7];
    reinterpret_cast<uint4*>(dst)[0] = o0;
    reinterpret_cast<uint4*>(dst)[1] = o1;
}

// ------- fused: cast x->bf16 + gate (blocks 0..1023) + w1 transpose -------
__global__ __launch_bounds__(256) void castgate_w1t_kernel(
    const float* __restrict__ x, const float* __restrict__ gW,
    const float* __restrict__ gb, const int* __restrict__ topk,
    u16* __restrict__ XB, float* __restrict__ scores,
    const float* __restrict__ w1, u16* __restrict__ W1T)
{
    const int t = threadIdx.x;
    if (blockIdx.x >= 1024) {
        // w1 transpose: 64x64 tile
        __shared__ float tile[64][65];
        const int tid = blockIdx.x - 1024;       // 0..511
        const int ct = tid & 127, rt = tid >> 7; // 128 col-tiles, 4 row-tiles
        const int r0 = rt * 64, c0 = ct * 64;
        #pragma unroll
        for (int i = 0; i < 4; ++i) {
            int idx = t + i * 256;
            int r = idx >> 4;
            int c = (idx & 15) * 4;
            float4 f = *reinterpret_cast<const float4*>(&w1[(long)(r0 + r) * 8192 + c0 + c]);
            tile[r][c] = f.x; tile[r][c + 1] = f.y; tile[r][c + 2] = f.z; tile[r][c + 3] = f.w;
        }
        __syncthreads();
        #pragma unroll
        for (int i = 0; i < 4; ++i) {
            int idx = t + i * 256;
            int rr = idx >> 4;
            int cc = idx & 15;
            u32 p0 = (u32)f2b(tile[cc * 4 + 0][rr]) | ((u32)f2b(tile[cc * 4 + 1][rr]) << 16);
            u32 p1 = (u32)f2b(tile[cc * 4 + 2][rr]) | ((u32)f2b(tile[cc * 4 + 3][rr]) << 16);
            uint2 o2; o2.x = p0; o2.y = p1;
            *reinterpret_cast<uint2*>(&W1T[(long)(c0 + rr) * 256 + r0 + cc * 4]) = o2;
        }
        return;
    }
    {
        int i = blockIdx.x * 256 + t;
        float4 f = reinterpret_cast<const float4*>(x)[i];
        u32 lo = (u32)f2b(f.x) | ((u32)f2b(f.y) << 16);
        u32 hi = (u32)f2b(f.z) | ((u32)f2b(f.w) << 16);
        uint2 o; o.x = lo; o.y = hi;
        reinterpret_cast<uint2*>(XB)[i] = o;
    }
    const int row = blockIdx.x * 4 + (t >> 6);
    const int l = t & 63;
    const int m = l & 15;
    const int q = l >> 4;
    const int Kk = *topk;
    const float* xr = x + (long)row * 256;
    float p = 0.f;
    #pragma unroll
    for (int k4 = 0; k4 < 16; ++k4) {
        f32x4 xv = *reinterpret_cast<const f32x4*>(xr + q * 64 + k4 * 4);
        const int kb = q * 64 + k4 * 4;
        p += xv[0] * gW[(kb + 0) * 16 + m] + xv[1] * gW[(kb + 1) * 16 + m]
           + xv[2] * gW[(kb + 2) * 16 + m] + xv[3] * gW[(kb + 3) * 16 + m];
    }
    p += __shfl_xor(p, 16);
    p += __shfl_xor(p, 32);
    float logit = p + gb[m];
    float mx = logit;
    #pragma unroll
    for (int d = 1; d < 16; d <<= 1) mx = fmaxf(mx, __shfl_xor(mx, d));
    int rank = 0;
    #pragma unroll
    for (int j = 0; j < 16; ++j) {
        float vj = __shfl(logit, (l & 48) | j);
        rank += (vj > logit) || (vj == logit && j < m);
    }
    bool sel = rank < Kk;
    float e = sel ? expf(logit - mx) : 0.f;
    float ssum = e;
    #pragma unroll
    for (int d = 1; d < 16; d <<= 1) ssum += __shfl_xor(ssum, d);
    if (q == 0) scores[row * 16 + m] = e / ssum;
}

// ---------------- LN + ReLU -> bf16 (one block per row, N=8192, bf16 input) ----------------
__global__ __launch_bounds__(256) void ln1_kernel(
    const u16* __restrict__ Y, const float* __restrict__ fcb,
    const float* __restrict__ g, const float* __restrict__ be,
    u16* __restrict__ H)
{
    const int N = 8192;
    const int row = blockIdx.x;
    const int t = threadIdx.x;
    const u16* y = Y + (long)row * N;
    const int base = t * 32;
    float v[32];
    float s = 0.f, s2 = 0.f;
    #pragma unroll
    for (int j = 0; j < 4; ++j) {
        uint4 q = *reinterpret_cast<const uint4*>(y + base + j * 8);
        f32x4 cA = *reinterpret_cast<const f32x4*>(fcb + base + j * 8);
        f32x4 cB = *reinterpret_cast<const f32x4*>(fcb + base + j * 8 + 4);
        const u32 ww[4] = {q.x, q.y, q.z, q.w};
        const float cb[8] = {cA[0], cA[1], cA[2], cA[3], cB[0], cB[1], cB[2], cB[3]};
        #pragma unroll
        for (int e = 0; e < 4; ++e) {
            float a0 = b2f((u16)(ww[e] & 0xffff)) + cb[e * 2];
            float a1 = b2f((u16)(ww[e] >> 16)) + cb[e * 2 + 1];
            v[j * 8 + e * 2] = a0; v[j * 8 + e * 2 + 1] = a1;
            s += a0 + a1;
            s2 += a0 * a0 + a1 * a1;
        }
    }
    #pragma unroll
    for (int d = 32; d > 0; d >>= 1) { s += __shfl_down(s, d); s2 += __shfl_down(s2, d); }
    __shared__ float red[8];
    if ((t & 63) == 0) { red[t >> 6] = s; red[4 + (t >> 6)] = s2; }
    __syncthreads();
    s = red[0] + red[1] + red[2] + red[3];
    s2 = red[4] + red[5] + red[6] + red[7];
    float mu = s * (1.f / N);
    float var = s2 * (1.f / N) - mu * mu;
    float rs = rsqrtf(var + 1e-5f);
    __align__(16) u16 o[32];
    #pragma unroll
    for (int j = 0; j < 4; ++j) {
        f32x4 gA = *reinterpret_cast<const f32x4*>(g + base + j * 8);
        f32x4 gB = *reinterpret_cast<const f32x4*>(g + base + j * 8 + 4);
        f32x4 eA = *reinterpret_cast<const f32x4*>(be + base + j * 8);
        f32x4 eB = *reinterpret_cast<const f32x4*>(be + base + j * 8 + 4);
        const float gg[8] = {gA[0], gA[1], gA[2], gA[3], gB[0], gB[1], gB[2], gB[3]};
        const float ee[8] = {eA[0], eA[1], eA[2], eA[3], eB[0], eB[1], eB[2], eB[3]};
        #pragma unroll
        for (int k = 0; k < 8; ++k) {
            float z = (v[j * 8 + k] - mu) * rs * gg[k] + ee[k];
            o[j * 8 + k] = f2b(fmaxf(z, 0.f));
        }
    }
    u16* h = H + (long)row * N + base;
    #pragma unroll
    for (int j = 0; j < 4; ++j)
        *reinterpret_cast<uint4*>(h + j * 8) = *reinterpret_cast<const uint4*>(&o[j * 8]);
}

// ---------------- LN2 + ReLU + expert-mix + heads (one block per row) ----------------
__global__ __launch_bounds__(256) void ln2_mix_heads_kernel(
    const u16* __restrict__ Y, const float* __restrict__ fcb,
    const float* __restrict__ g, const float* __restrict__ be,
    const float* __restrict__ scores,
    const float* __restrict__ mW, const float* __restrict__ mb,
    const float* __restrict__ sW, const float* __restrict__ sb,
    float* __restrict__ out)
{
    const int N = 8192;
    const int B = 4096;
    const int row = blockIdx.x;
    const int t = threadIdx.x;
    const u16* y = Y + (long)row * N;
    const int base = t * 32;
    __shared__ float sc[16];
    if (t < 16) sc[t] = scores[row * 16 + t];
    float v[32];
    float s = 0.f, s2 = 0.f;
    #pragma unroll
    for (int j = 0; j < 4; ++j) {
        uint4 q = *reinterpret_cast<const uint4*>(y + base + j * 8);
        f32x4 cA = *reinterpret_cast<const f32x4*>(fcb + base + j * 8);
        f32x4 cB = *reinterpret_cast<const f32x4*>(fcb + base + j * 8 + 4);
        const u32 ww[4] = {q.x, q.y, q.z, q.w};
        const float cb[8] = {cA[0], cA[1], cA[2], cA[3], cB[0], cB[1], cB[2], cB[3]};
        #pragma unroll
        for (int e = 0; e < 4; ++e) {
            float a0 = b2f((u16)(ww[e] & 0xffff)) + cb[e * 2];
            float a1 = b2f((u16)(ww[e] >> 16)) + cb[e * 2 + 1];
            v[j * 8 + e * 2] = a0; v[j * 8 + e * 2 + 1] = a1;
            s += a0 + a1;
            s2 += a0 * a0 + a1 * a1;
        }
    }
    #pragma unroll
    for (int d = 32; d > 0; d >>= 1) { s += __shfl_down(s, d); s2 += __shfl_down(s2, d); }
    __shared__ float red[8];
    if ((t & 63) == 0) { red[t >> 6] = s; red[4 + (t >> 6)] = s2; }
    __syncthreads();
    s = red[0] + red[1] + red[2] + red[3];
    s2 = red[4] + red[5] + red[6] + red[7];
    float mu = s * (1.f / N);
    float var = s2 * (1.f / N) - mu * mu;
    float rs = rsqrtf(var + 1e-5f);
    float m0 = 0.f, m1 = 0.f;
    #pragma unroll
    for (int j = 0; j < 4; ++j) {
        f32x4 g0 = *reinterpret_cast<const f32x4*>(g + base + j * 4);
        f32x4 e0 = *reinterpret_cast<const f32x4*>(be + base + j * 4);
        f32x4 g1 = *reinterpret_cast<const f32x4*>(g + base + 16 + j * 4);
        f32x4 e1 = *reinterpret_cast<const f32x4*>(be + base + 16 + j * 4);
        #pragma unroll
        for (int k = 0; k < 4; ++k) {
            int m = j * 4 + k;
            float z0 = fmaxf((v[m] - mu) * rs * g0[k] + e0[k], 0.f);
            float z1 = fmaxf((v[16 + m] - mu) * rs * g1[k] + e1[k], 0.f);
            m0 += z0 * sc[m];
            m1 += z1 * sc[m];
        }
    }
    __shared__ float mix[512];
    mix[2 * t]     = m0 * (1.f / 16.f);
    mix[2 * t + 1] = m1 * (1.f / 16.f);
    __syncthreads();
    const int a = t & 31;
    const int seg = t >> 5;
    float pm = 0.f, ps = 0.f;
    #pragma unroll 4
    for (int h = seg * 64; h < seg * 64 + 64; ++h) {
        float xv = mix[h];
        pm += xv * mW[h * 32 + a];
        ps += xv * sW[h * 32 + a];
    }
    __shared__ float prm[8][32];
    __shared__ float prs[8][32];
    prm[seg][a] = pm;
    prs[seg][a] = ps;
    __syncthreads();
    if (t < 32) {
        float am = mb[t];
        #pragma unroll
        for (int ss = 0; ss < 8; ++ss) am += prm[ss][t];
        out[(long)row * 32 + t] = am;
    } else if (t < 64) {
        int aa = t - 32;
        float as = sb[aa];
        #pragma unroll
        for (int ss = 0; ss < 8; ++ss) as += prs[ss][aa];
        float ts = tanhf(as);
        out[(long)B * 32 + (long)row * 32 + aa] = -5.0f + 3.5f * (ts + 1.0f);
    }
}

extern "C" void kernel_launch(void* const* d_in, const int* in_sizes, int n_in,
                              void* d_out, int out_size, void* d_ws, size_t ws_size,
                              hipStream_t stream) {
    const float* x   = (const float*)d_in[0];
    const float* gW  = (const float*)d_in[1];
    const float* gb  = (const float*)d_in[2];
    const float* w1  = (const float*)d_in[3];
    const float* b1  = (const float*)d_in[4];
    const float* g1  = (const float*)d_in[5];
    const float* be1 = (const float*)d_in[6];
    const float* w2  = (const float*)d_in[7];
    const float* b2  = (const float*)d_in[8];
    const float* g2  = (const float*)d_in[9];
    const float* be2 = (const float*)d_in[10];
    const float* mW  = (const float*)d_in[11];
    const float* mb  = (const float*)d_in[12];
    const float* sW  = (const float*)d_in[13];
    const float* sb  = (const float*)d_in[14];
    const int* topk  = (const int*)d_in[15];
    float* out = (float*)d_out;

    char* ws = (char*)d_ws;
    u16* W2T = (u16*)ws;            ws += (long)8192 * 8192 * 2;   // 128 MB
    u16* Yb = (u16*)ws;             ws += (long)4096 * 8192 * 2;   //  64 MB
    u16* H1 = (u16*)ws;             ws += (long)4096 * 8192 * 2;   //  64 MB
    u16* W1T = (u16*)ws;            ws += (long)8192 * 256 * 2;    //   4 MB
    u16* XB = (u16*)ws;             ws += (long)4096 * 256 * 2;    //   2 MB
    float* SCR = (float*)ws;        ws += (long)4096 * 16 * 4;

    // 1. cast+gate (1024 blocks) + w1 transpose (512 blocks)
    castgate_w1t_kernel<<<1536, 256, 0, stream>>>(x, gW, gb, topk, XB, SCR, w1, W1T);

    // 2. fc1 GEMM (512 blocks) overlapped with w2 transpose (8192 blocks)
    fc1_w2t_kernel<<<512 + 8192, 512, 0, stream>>>(XB, W1T, Yb, w2, W2T);

    // 3. LN1+ReLU -> bf16
    ln1_kernel<<<4096, 256, 0, stream>>>(Yb, b1, g1, be1, H1);

    // 4. fc2 GEMM
    gemm256<<<dim3(32, 16), 512, 0, stream>>>(H1, 8192, W2T, 8192, Yb, 8192, 8192);

    // 5. LN2+ReLU+mix+heads
    ln2_mix_heads_kernel<<<4096, 256, 0, stream>>>(Yb, b2, g2, be2, SCR,
                                                   mW, mb, sW, sb, out);
}

// Round 12
// 704.553 us; speedup vs baseline: 1.0339x; 1.0339x over previous
//
#include <hip/hip_runtime.h>
#include <hip/hip_bf16.h>

typedef unsigned int u32;
typedef unsigned short u16;
typedef __bf16 bf16x8 __attribute__((ext_vector_type(8)));
typedef float f32x4 __attribute__((ext_vector_type(4)));

__device__ __forceinline__ u16 f2b(float f) {
    __bf16 b = (__bf16)f;
    return __builtin_bit_cast(u16, b);
}
__device__ __forceinline__ float b2f(u16 v) {
    u32 x = ((u32)v) << 16;
    return __builtin_bit_cast(float, x);
}

__device__ __forceinline__ void gld_lds16(const void* g, void* l) {
    __builtin_amdgcn_global_load_lds(
        (const __attribute__((address_space(1))) u32*)(size_t)g,
        (__attribute__((address_space(3))) u32*)(u32)(size_t)l,
        16, 0, 0);
}

#define BARRIER __builtin_amdgcn_s_barrier()
#define LGKM0 asm volatile("s_waitcnt lgkmcnt(0)" ::: "memory")
#define VMC4 asm volatile("s_waitcnt vmcnt(4)" ::: "memory")
#define VMC6 asm volatile("s_waitcnt vmcnt(6)" ::: "memory")
#define VMC0 asm volatile("s_waitcnt vmcnt(0)" ::: "memory")
#define MFMA16(d, a, b) d = __builtin_amdgcn_mfma_f32_16x16x32_bf16(a, b, d, 0, 0, 0)

// ---------------- fused cast x->bf16 + gate softmax/topk ----------------
__global__ __launch_bounds__(256) void castgate_kernel(
    const float* __restrict__ x, const float* __restrict__ gW,
    const float* __restrict__ gb, const int* __restrict__ topk,
    u16* __restrict__ XB, float* __restrict__ scores)
{
    const int t = threadIdx.x;
    {
        int i = blockIdx.x * 256 + t;
        float4 f = reinterpret_cast<const float4*>(x)[i];
        u32 lo = (u32)f2b(f.x) | ((u32)f2b(f.y) << 16);
        u32 hi = (u32)f2b(f.z) | ((u32)f2b(f.w) << 16);
        uint2 o; o.x = lo; o.y = hi;
        reinterpret_cast<uint2*>(XB)[i] = o;
    }
    const int row = blockIdx.x * 4 + (t >> 6);
    const int l = t & 63;
    const int m = l & 15;
    const int q = l >> 4;
    const int Kk = *topk;
    const float* xr = x + (long)row * 256;
    float p = 0.f;
    #pragma unroll
    for (int k4 = 0; k4 < 16; ++k4) {
        f32x4 xv = *reinterpret_cast<const f32x4*>(xr + q * 64 + k4 * 4);
        const int kb = q * 64 + k4 * 4;
        p += xv[0] * gW[(kb + 0) * 16 + m] + xv[1] * gW[(kb + 1) * 16 + m]
           + xv[2] * gW[(kb + 2) * 16 + m] + xv[3] * gW[(kb + 3) * 16 + m];
    }
    p += __shfl_xor(p, 16);
    p += __shfl_xor(p, 32);
    float logit = p + gb[m];
    float mx = logit;
    #pragma unroll
    for (int d = 1; d < 16; d <<= 1) mx = fmaxf(mx, __shfl_xor(mx, d));
    int rank = 0;
    #pragma unroll
    for (int j = 0; j < 16; ++j) {
        float vj = __shfl(logit, (l & 48) | j);
        rank += (vj > logit) || (vj == logit && j < m);
    }
    bool sel = rank < Kk;
    float e = sel ? expf(logit - mx) : 0.f;
    float ssum = e;
    #pragma unroll
    for (int d = 1; d < 16; d <<= 1) ssum += __shfl_xor(ssum, d);
    if (q == 0) scores[row * 16 + m] = e / ssum;
}

// ---------------- transpose + cast both weights in one launch ----------------
__global__ __launch_bounds__(256) void transpose_both_kernel(
    const float* __restrict__ w2, u16* __restrict__ W2T,
    const float* __restrict__ w1, u16* __restrict__ W1T)
{
    __shared__ float tile[64][65];
    const int t = threadIdx.x;
    const int byy = blockIdx.y;
    const float* in;
    u16* outp;
    int R, r0;
    if (byy < 128) { in = w2; outp = W2T; R = 8192; r0 = byy * 64; }
    else           { in = w1; outp = W1T; R = 256;  r0 = (byy - 128) * 64; }
    const int C = 8192;
    const int c0 = blockIdx.x * 64;
    #pragma unroll
    for (int i = 0; i < 4; ++i) {
        int idx = t + i * 256;
        int r = idx >> 4;
        int c = (idx & 15) * 4;
        float4 f = *reinterpret_cast<const float4*>(&in[(long)(r0 + r) * C + c0 + c]);
        tile[r][c] = f.x; tile[r][c + 1] = f.y; tile[r][c + 2] = f.z; tile[r][c + 3] = f.w;
    }
    __syncthreads();
    #pragma unroll
    for (int i = 0; i < 4; ++i) {
        int idx = t + i * 256;
        int rr = idx >> 4;        // output row within tile (= input col)
        int cc = idx & 15;        // group of 4 output cols (= input rows)
        u32 p0 = (u32)f2b(tile[cc * 4 + 0][rr]) | ((u32)f2b(tile[cc * 4 + 1][rr]) << 16);
        u32 p1 = (u32)f2b(tile[cc * 4 + 2][rr]) | ((u32)f2b(tile[cc * 4 + 3][rr]) << 16);
        uint2 o2; o2.x = p0; o2.y = p1;
        *reinterpret_cast<uint2*>(&outp[(long)(c0 + rr) * R + r0 + cc * 4]) = o2;
    }
}

// ================= 256x256 8-phase bf16 GEMM (16x16x32 MFMA) =================
// Round-9 validated schedule: 8 waves (2Mx4N), BK=64, 128 KiB LDS,
// XOR swizzle byte^=((row&7)<<4), read balance 8/4/8/4 with bL pipelined
// one K-tile ahead (VMC4 at P3-end), P4 MFMA reg-only (no entry barrier).

template<int GRAN>
__device__ __forceinline__ void stage_half(
    const u16* __restrict__ src, int ld, int rowbase, int kk,
    u16* ldsregion, int h, int w, int l)
{
    #pragma unroll
    for (int j = 0; j < 2; ++j) {
        const int c = w * 2 + j;
        const int o = c * 1024 + l * 16;               // linear dest byte in 16KB half
        const int os = o ^ (((o >> 7) & 7) << 4);      // inverse-swizzled source offset
        const int pos = o >> 7;                        // lds row
        const int row = ((pos / GRAN) * 2 + h) * GRAN + (pos & (GRAN - 1));
        const u16* g = src + (long)(rowbase + row) * ld + kk + ((os & 127) >> 1);
        gld_lds16(g, ldsregion + c * 512);
    }
}

__device__ __forceinline__ bf16x8 ldfrag(const u16* region, int pos, int col) {
    const int o = (pos * 128 + col * 2) ^ ((pos & 7) << 4);
    return *reinterpret_cast<const bf16x8*>(reinterpret_cast<const char*>(region) + o);
}

template<int CB>
__device__ __forceinline__ void ktile_group(
    const u16* __restrict__ A, int lda, const u16* __restrict__ BT, int ldb,
    int brow, int bcol, int kkA1, int kkR,
    int wr, int wc, int r4, int q8, int w, int l,
    u16 (&lds)[2][4][8192], f32x4 (&acc)[8][4],
    bf16x8 (&bLu)[2][2], bf16x8 (&bLf)[2][2])
{
    bf16x8 aL[4][2], aH[4][2], bH[2][2];

    // ---- P1: quadrant (m0-3, n0-1); reads aL (8)
    #pragma unroll
    for (int m = 0; m < 4; ++m) {
        aL[m][0] = ldfrag(lds[CB][0], wr * 64 + m * 16 + r4, q8);
        aL[m][1] = ldfrag(lds[CB][0], wr * 64 + m * 16 + r4, 32 + q8);
    }
    stage_half<64>(A, lda, brow, kkA1, &lds[1 - CB][1][0], 1, w, l);
    BARRIER; LGKM0;
    __builtin_amdgcn_s_setprio(1);
    #pragma unroll
    for (int m = 0; m < 4; ++m)
        #pragma unroll
        for (int n = 0; n < 2; ++n) {
            MFMA16(acc[m][n], aL[m][0], bLu[n][0]);
            MFMA16(acc[m][n], aL[m][1], bLu[n][1]);
        }
    __builtin_amdgcn_s_setprio(0);
    BARRIER;

    // ---- P2: quadrant (m0-3, n2-3); reads bH (4)
    #pragma unroll
    for (int n = 0; n < 2; ++n) {
        bH[n][0] = ldfrag(lds[CB][3], wc * 32 + n * 16 + r4, q8);
        bH[n][1] = ldfrag(lds[CB][3], wc * 32 + n * 16 + r4, 32 + q8);
    }
    stage_half<64>(A, lda, brow, kkR, &lds[CB][0][0], 0, w, l);
    BARRIER; LGKM0;
    __builtin_amdgcn_s_setprio(1);
    #pragma unroll
    for (int m = 0; m < 4; ++m)
        #pragma unroll
        for (int n = 0; n < 2; ++n) {
            MFMA16(acc[m][2 + n], aL[m][0], bH[n][0]);
            MFMA16(acc[m][2 + n], aL[m][1], bH[n][1]);
        }
    __builtin_amdgcn_s_setprio(0);
    BARRIER;

    // ---- P3: quadrant (m4-7, n2-3); reads aH (8); VMC4 certifies other buffer
    #pragma unroll
    for (int m = 0; m < 4; ++m) {
        aH[m][0] = ldfrag(lds[CB][1], wr * 64 + m * 16 + r4, q8);
        aH[m][1] = ldfrag(lds[CB][1], wr * 64 + m * 16 + r4, 32 + q8);
    }
    stage_half<32>(BT, ldb, bcol, kkR, &lds[CB][2][0], 0, w, l);
    BARRIER; LGKM0;
    __builtin_amdgcn_s_setprio(1);
    #pragma unroll
    for (int m = 0; m < 4; ++m)
        #pragma unroll
        for (int n = 0; n < 2; ++n) {
            MFMA16(acc[4 + m][2 + n], aH[m][0], bH[n][0]);
            MFMA16(acc[4 + m][2 + n], aH[m][1], bH[n][1]);
        }
    __builtin_amdgcn_s_setprio(0);
    VMC4;
    BARRIER;

    // ---- P4: quadrant (m4-7, n0-1); register-only MFMA -> no entry barrier.
    stage_half<32>(BT, ldb, bcol, kkR, &lds[CB][3][0], 1, w, l);
    #pragma unroll
    for (int n = 0; n < 2; ++n) {
        bLf[n][0] = ldfrag(lds[1 - CB][2], wc * 32 + n * 16 + r4, q8);
        bLf[n][1] = ldfrag(lds[1 - CB][2], wc * 32 + n * 16 + r4, 32 + q8);
    }
    __builtin_amdgcn_s_setprio(1);
    #pragma unroll
    for (int m = 0; m < 4; ++m)
        #pragma unroll
        for (int n = 0; n < 2; ++n) {
            MFMA16(acc[4 + m][n], aH[m][0], bLu[n][0]);
            MFMA16(acc[4 + m][n], aH[m][1], bLu[n][1]);
        }
    __builtin_amdgcn_s_setprio(0);
    BARRIER;
}

__global__ __launch_bounds__(512, 2) void gemm256(
    const u16* __restrict__ A, int lda,
    const u16* __restrict__ BT, int ldb,
    u16* __restrict__ C, int ldc, int K)
{
    __shared__ __align__(16) u16 lds[2][4][8192];   // 128 KiB
    const int t = threadIdx.x;
    const int w = t >> 6, l = t & 63;
    const int wr = w >> 2, wc = w & 3;
    const int r4 = l & 15, q8 = (l >> 4) * 8;
    const int bid = blockIdx.y * 32 + blockIdx.x;
    const int xcd = bid & 7, within = bid >> 3;
    const int by = (xcd >> 2) * 8 + (within >> 3);
    const int bx = (xcd & 3) * 8 + (within & 7);
    const int brow = by * 256, bcol = bx * 256;
    const int NT = K >> 6;

    f32x4 acc[8][4];
    #pragma unroll
    for (int m = 0; m < 8; ++m)
        #pragma unroll
        for (int n = 0; n < 4; ++n)
            acc[m][n] = (f32x4){0.f, 0.f, 0.f, 0.f};

    stage_half<64>(A, lda, brow, 0, &lds[0][0][0], 0, w, l);
    stage_half<32>(BT, ldb, bcol, 0, &lds[0][2][0], 0, w, l);
    stage_half<32>(BT, ldb, bcol, 0, &lds[0][3][0], 1, w, l);
    stage_half<64>(A, lda, brow, 0, &lds[0][1][0], 1, w, l);
    stage_half<64>(A, lda, brow, 64, &lds[1][0][0], 0, w, l);
    stage_half<32>(BT, ldb, bcol, 64, &lds[1][2][0], 0, w, l);
    stage_half<32>(BT, ldb, bcol, 64, &lds[1][3][0], 1, w, l);
    VMC6;
    BARRIER;

    bf16x8 bl0[2][2], bl1[2][2];
    #pragma unroll
    for (int n = 0; n < 2; ++n) {
        bl0[n][0] = ldfrag(lds[0][2], wc * 32 + n * 16 + r4, q8);
        bl0[n][1] = ldfrag(lds[0][2], wc * 32 + n * 16 + r4, 32 + q8);
    }

    for (int i = 0; i < (NT >> 1); ++i) {
        const int U = 2 * i;
        int tV = U + 1;
        int tU2 = U + 2;
        int tV2 = U + 3;
        if (tU2 >= NT) tU2 -= NT;
        if (tV2 >= NT) tV2 -= NT;
        const int kkV = (tV >= NT ? tV - NT : tV) << 6;
        const int kkU2 = tU2 << 6;
        const int kkV2 = tV2 << 6;

        ktile_group<0>(A, lda, BT, ldb, brow, bcol, kkV, kkU2,
                       wr, wc, r4, q8, w, l, lds, acc, bl0, bl1);
        ktile_group<1>(A, lda, BT, ldb, brow, bcol, kkU2, kkV2,
                       wr, wc, r4, q8, w, l, lds, acc, bl1, bl0);
    }

    VMC0;

    const int crow0 = (l >> 4) * 4;
    const int ccol = l & 15;
    #pragma unroll
    for (int m = 0; m < 8; ++m) {
        #pragma unroll
        for (int n = 0; n < 4; ++n) {
            int gr = brow + wr * 128 + m * 16 + crow0;
            int gc = bcol + wc * 64 + n * 16 + ccol;
            #pragma unroll
            for (int r = 0; r < 4; ++r)
                C[(long)(gr + r) * ldc + gc] = f2b(acc[m][n][r]);
        }
    }
}

// ---------------- LN + ReLU -> bf16 (one block per row, N=8192, bf16 input) ----------------
__global__ __launch_bounds__(256) void ln1_kernel(
    const u16* __restrict__ Y, const float* __restrict__ fcb,
    const float* __restrict__ g, const float* __restrict__ be,
    u16* __restrict__ H)
{
    const int N = 8192;
    const int row = blockIdx.x;
    const int t = threadIdx.x;
    const u16* y = Y + (long)row * N;
    const int base = t * 32;
    float v[32];
    float s = 0.f, s2 = 0.f;
    #pragma unroll
    for (int j = 0; j < 4; ++j) {
        uint4 q = *reinterpret_cast<const uint4*>(y + base + j * 8);
        f32x4 cA = *reinterpret_cast<const f32x4*>(fcb + base + j * 8);
        f32x4 cB = *reinterpret_cast<const f32x4*>(fcb + base + j * 8 + 4);
        const u32 ww[4] = {q.x, q.y, q.z, q.w};
        const float cb[8] = {cA[0], cA[1], cA[2], cA[3], cB[0], cB[1], cB[2], cB[3]};
        #pragma unroll
        for (int e = 0; e < 4; ++e) {
            float a0 = b2f((u16)(ww[e] & 0xffff)) + cb[e * 2];
            float a1 = b2f((u16)(ww[e] >> 16)) + cb[e * 2 + 1];
            v[j * 8 + e * 2] = a0; v[j * 8 + e * 2 + 1] = a1;
            s += a0 + a1;
            s2 += a0 * a0 + a1 * a1;
        }
    }
    #pragma unroll
    for (int d = 32; d > 0; d >>= 1) { s += __shfl_down(s, d); s2 += __shfl_down(s2, d); }
    __shared__ float red[8];
    if ((t & 63) == 0) { red[t >> 6] = s; red[4 + (t >> 6)] = s2; }
    __syncthreads();
    s = red[0] + red[1] + red[2] + red[3];
    s2 = red[4] + red[5] + red[6] + red[7];
    float mu = s * (1.f / N);
    float var = s2 * (1.f / N) - mu * mu;
    float rs = rsqrtf(var + 1e-5f);
    __align__(16) u16 o[32];
    #pragma unroll
    for (int j = 0; j < 4; ++j) {
        f32x4 gA = *reinterpret_cast<const f32x4*>(g + base + j * 8);
        f32x4 gB = *reinterpret_cast<const f32x4*>(g + base + j * 8 + 4);
        f32x4 eA = *reinterpret_cast<const f32x4*>(be + base + j * 8);
        f32x4 eB = *reinterpret_cast<const f32x4*>(be + base + j * 8 + 4);
        const float gg[8] = {gA[0], gA[1], gA[2], gA[3], gB[0], gB[1], gB[2], gB[3]};
        const float ee[8] = {eA[0], eA[1], eA[2], eA[3], eB[0], eB[1], eB[2], eB[3]};
        #pragma unroll
        for (int k = 0; k < 8; ++k) {
            float z = (v[j * 8 + k] - mu) * rs * gg[k] + ee[k];
            o[j * 8 + k] = f2b(fmaxf(z, 0.f));
        }
    }
    u16* h = H + (long)row * N + base;
    #pragma unroll
    for (int j = 0; j < 4; ++j)
        *reinterpret_cast<uint4*>(h + j * 8) = *reinterpret_cast<const uint4*>(&o[j * 8]);
}

// ---------------- LN2 + ReLU + expert-mix + heads (one block per row) ----------------
__global__ __launch_bounds__(256) void ln2_mix_heads_kernel(
    const u16* __restrict__ Y, const float* __restrict__ fcb,
    const float* __restrict__ g, const float* __restrict__ be,
    const float* __restrict__ scores,
    const float* __restrict__ mW, const float* __restrict__ mb,
    const float* __restrict__ sW, const float* __restrict__ sb,
    float* __restrict__ out)
{
    const int N = 8192;
    const int B = 4096;
    const int row = blockIdx.x;
    const int t = threadIdx.x;
    const u16* y = Y + (long)row * N;
    const int base = t * 32;
    __shared__ float sc[16];
    if (t < 16) sc[t] = scores[row * 16 + t];
    float v[32];
    float s = 0.f, s2 = 0.f;
    #pragma unroll
    for (int j = 0; j < 4; ++j) {
        uint4 q = *reinterpret_cast<const uint4*>(y + base + j * 8);
        f32x4 cA = *reinterpret_cast<const f32x4*>(fcb + base + j * 8);
        f32x4 cB = *reinterpret_cast<const f32x4*>(fcb + base + j * 8 + 4);
        const u32 ww[4] = {q.x, q.y, q.z, q.w};
        const float cb[8] = {cA[0], cA[1], cA[2], cA[3], cB[0], cB[1], cB[2], cB[3]};
        #pragma unroll
        for (int e = 0; e < 4; ++e) {
            float a0 = b2f((u16)(ww[e] & 0xffff)) + cb[e * 2];
            float a1 = b2f((u16)(ww[e] >> 16)) + cb[e * 2 + 1];
            v[j * 8 + e * 2] = a0; v[j * 8 + e * 2 + 1] = a1;
            s += a0 + a1;
            s2 += a0 * a0 + a1 * a1;
        }
    }
    #pragma unroll
    for (int d = 32; d > 0; d >>= 1) { s += __shfl_down(s, d); s2 += __shfl_down(s2, d); }
    __shared__ float red[8];
    if ((t & 63) == 0) { red[t >> 6] = s; red[4 + (t >> 6)] = s2; }
    __syncthreads();
    s = red[0] + red[1] + red[2] + red[3];
    s2 = red[4] + red[5] + red[6] + red[7];
    float mu = s * (1.f / N);
    float var = s2 * (1.f / N) - mu * mu;
    float rs = rsqrtf(var + 1e-5f);
    float m0 = 0.f, m1 = 0.f;
    #pragma unroll
    for (int j = 0; j < 4; ++j) {
        f32x4 g0 = *reinterpret_cast<const f32x4*>(g + base + j * 4);
        f32x4 e0 = *reinterpret_cast<const f32x4*>(be + base + j * 4);
        f32x4 g1 = *reinterpret_cast<const f32x4*>(g + base + 16 + j * 4);
        f32x4 e1 = *reinterpret_cast<const f32x4*>(be + base + 16 + j * 4);
        #pragma unroll
        for (int k = 0; k < 4; ++k) {
            int m = j * 4 + k;
            float z0 = fmaxf((v[m] - mu) * rs * g0[k] + e0[k], 0.f);
            float z1 = fmaxf((v[16 + m] - mu) * rs * g1[k] + e1[k], 0.f);
            m0 += z0 * sc[m];
            m1 += z1 * sc[m];
        }
    }
    __shared__ float mix[512];
    mix[2 * t]     = m0 * (1.f / 16.f);
    mix[2 * t + 1] = m1 * (1.f / 16.f);
    __syncthreads();
    const int a = t & 31;
    const int seg = t >> 5;
    float pm = 0.f, ps = 0.f;
    #pragma unroll 4
    for (int h = seg * 64; h < seg * 64 + 64; ++h) {
        float xv = mix[h];
        pm += xv * mW[h * 32 + a];
        ps += xv * sW[h * 32 + a];
    }
    __shared__ float prm[8][32];
    __shared__ float prs[8][32];
    prm[seg][a] = pm;
    prs[seg][a] = ps;
    __syncthreads();
    if (t < 32) {
        float am = mb[t];
        #pragma unroll
        for (int ss = 0; ss < 8; ++ss) am += prm[ss][t];
        out[(long)row * 32 + t] = am;
    } else if (t < 64) {
        int aa = t - 32;
        float as = sb[aa];
        #pragma unroll
        for (int ss = 0; ss < 8; ++ss) as += prs[ss][aa];
        float ts = tanhf(as);
        out[(long)B * 32 + (long)row * 32 + aa] = -5.0f + 3.5f * (ts + 1.0f);
    }
}

extern "C" void kernel_launch(void* const* d_in, const int* in_sizes, int n_in,
                              void* d_out, int out_size, void* d_ws, size_t ws_size,
                              hipStream_t stream) {
    const float* x   = (const float*)d_in[0];
    const float* gW  = (const float*)d_in[1];
    const float* gb  = (const float*)d_in[2];
    const float* w1  = (const float*)d_in[3];
    const float* b1  = (const float*)d_in[4];
    const float* g1  = (const float*)d_in[5];
    const float* be1 = (const float*)d_in[6];
    const float* w2  = (const float*)d_in[7];
    const float* b2  = (const float*)d_in[8];
    const float* g2  = (const float*)d_in[9];
    const float* be2 = (const float*)d_in[10];
    const float* mW  = (const float*)d_in[11];
    const float* mb  = (const float*)d_in[12];
    const float* sW  = (const float*)d_in[13];
    const float* sb  = (const float*)d_in[14];
    const int* topk  = (const int*)d_in[15];
    float* out = (float*)d_out;

    char* ws = (char*)d_ws;
    u16* W2T = (u16*)ws;            ws += (long)8192 * 8192 * 2;   // 128 MB
    u16* Yb = (u16*)ws;             ws += (long)4096 * 8192 * 2;   //  64 MB
    u16* H1 = (u16*)ws;             ws += (long)4096 * 8192 * 2;   //  64 MB
    u16* W1T = (u16*)ws;            ws += (long)8192 * 256 * 2;    //   4 MB
    u16* XB = (u16*)ws;             ws += (long)4096 * 256 * 2;    //   2 MB
    float* SCR = (float*)ws;        ws += (long)4096 * 16 * 4;

    // prep: fused cast+gate, fused transposes
    castgate_kernel<<<1024, 256, 0, stream>>>(x, gW, gb, topk, XB, SCR);
    transpose_both_kernel<<<dim3(128, 132), 256, 0, stream>>>(w2, W2T, w1, W1T);

    // fc1 -> LN1+ReLU -> bf16
    gemm256<<<dim3(32, 16), 512, 0, stream>>>(XB, 256, W1T, 256, Yb, 8192, 256);
    ln1_kernel<<<4096, 256, 0, stream>>>(Yb, b1, g1, be1, H1);

    // fc2 -> LN2+ReLU+mix+heads
    gemm256<<<dim3(32, 16), 512, 0, stream>>>(H1, 8192, W2T, 8192, Yb, 8192, 8192);
    ln2_mix_heads_kernel<<<4096, 256, 0, stream>>>(Yb, b2, g2, be2, SCR,
                                                   mW, mb, sW, sb, out);
}